// Round 1
// 2188.712 us; speedup vs baseline: 1.0848x; 1.0848x over previous
//
#include <hip/hip_runtime.h>
#include <hip/hip_bf16.h>

#define V_SZ 50000
#define C_SZ 150000
#define E_SZ 800000
#define EPN  200000
#define ENN  200000
#define DIM  128
#define NITER 4
#define PITCH 136   // 128 + 8 shorts pad; 272 B row stride ≡ 16 (mod 128) -> conflict-free b128 reads

typedef __hip_bfloat16 bf16;
typedef __attribute__((ext_vector_type(8)))  short short8;
typedef __attribute__((ext_vector_type(16))) float floatx16;

__device__ __forceinline__ float bflo(unsigned u){ return __uint_as_float(u << 16); }
__device__ __forceinline__ float bfhi(unsigned u){ return __uint_as_float(u & 0xffff0000u); }
__device__ __forceinline__ short f2bf(float f){
  union { __hip_bfloat16 h; short s; } u; u.h = __float2bfloat16(f); return u.s;
}
__device__ __forceinline__ int pk2(float a, float b){
  union { short s[2]; int i; } u; u.s[0] = f2bf(a); u.s[1] = f2bf(b); return u.i;
}

// ---------------- setup kernels ----------------

__global__ void hist_kernel(const int* __restrict__ v_ei, const int* __restrict__ c_ei,
                            const int* __restrict__ p_ei, const int* __restrict__ n_ei,
                            int* __restrict__ pv, int* __restrict__ pc,
                            int* __restrict__ nv, int* __restrict__ nc,
                            int* __restrict__ p_v_deg, int* __restrict__ p_c_deg,
                            int* __restrict__ n_v_deg, int* __restrict__ n_c_deg) {
  int i = blockIdx.x * 256 + threadIdx.x;
  if (i < EPN) {
    int e = p_ei[i]; int v = v_ei[e]; int c = c_ei[e];
    pv[i] = v; pc[i] = c;
    atomicAdd(&p_v_deg[v], 1); atomicAdd(&p_c_deg[c], 1);
  } else if (i < EPN + ENN) {
    int j = i - EPN;
    int e = n_ei[j]; int v = v_ei[e]; int c = c_ei[e];
    nv[j] = v; nc[j] = c;
    atomicAdd(&n_v_deg[v], 1); atomicAdd(&n_c_deg[c], 1);
  }
}

__global__ void scan_phase1(const int* __restrict__ in, int* __restrict__ out,
                            int* __restrict__ bsum, int n) {
  __shared__ int sh[256];
  const int t = threadIdx.x;
  const int base = blockIdx.x * 1024 + t * 4;
  int v0 = (base + 0 < n) ? in[base + 0] : 0;
  int v1 = (base + 1 < n) ? in[base + 1] : 0;
  int v2 = (base + 2 < n) ? in[base + 2] : 0;
  int v3 = (base + 3 < n) ? in[base + 3] : 0;
  int s = v0 + v1 + v2 + v3;
  sh[t] = s; __syncthreads();
  for (int off = 1; off < 256; off <<= 1) {
    int x = (t >= off) ? sh[t - off] : 0;
    __syncthreads();
    sh[t] += x;
    __syncthreads();
  }
  int excl = sh[t] - s;
  if (base + 0 < n) out[base + 0] = excl;
  if (base + 1 < n) out[base + 1] = excl + v0;
  if (base + 2 < n) out[base + 2] = excl + v0 + v1;
  if (base + 3 < n) out[base + 3] = excl + v0 + v1 + v2;
  if (t == 255) bsum[blockIdx.x] = sh[255];
}

__global__ void scan_phase2(int* __restrict__ bsum, int nb, int* __restrict__ total_out) {
  __shared__ int sh[256];
  const int t = threadIdx.x;
  int v = (t < nb) ? bsum[t] : 0;
  sh[t] = v; __syncthreads();
  for (int off = 1; off < 256; off <<= 1) {
    int x = (t >= off) ? sh[t - off] : 0;
    __syncthreads();
    sh[t] += x;
    __syncthreads();
  }
  if (t < nb) bsum[t] = sh[t] - v;
  if (t == 255) *total_out = sh[255];
}

__global__ void scan_phase3(int* __restrict__ out, const int* __restrict__ bsum, int n) {
  int i = blockIdx.x * 256 + threadIdx.x;
  if (i < n) out[i] += bsum[i >> 10];
}

__global__ void fill_kernel(const int* __restrict__ pv, const int* __restrict__ pc,
                            const int* __restrict__ nv, const int* __restrict__ nc,
                            const int* __restrict__ p_v_deg, const int* __restrict__ p_c_deg,
                            const int* __restrict__ n_v_deg, const int* __restrict__ n_c_deg,
                            int* __restrict__ cur_cP, int* __restrict__ cur_cN,
                            int* __restrict__ cur_vP, int* __restrict__ cur_vN,
                            int2* __restrict__ el_cP, int2* __restrict__ el_cN,
                            int2* __restrict__ el_vP, int2* __restrict__ el_vN) {
  int i = blockIdx.x * 256 + threadIdx.x;
  if (i < EPN) {
    int v = pv[i], c = pc[i];
    float dv = (float)max(p_v_deg[v], 1);
    float dc = (float)max(p_c_deg[c], 1);
    int wb = __float_as_int(rsqrtf(dv * dc));
    int pos  = atomicAdd(&cur_cP[c], 1);
    if (pos >= 0 && pos < EPN) el_cP[pos] = make_int2(v, wb);
    int pos2 = atomicAdd(&cur_vP[v], 1);
    if (pos2 >= 0 && pos2 < EPN) el_vP[pos2] = make_int2(c, wb);
  } else if (i < EPN + ENN) {
    int j = i - EPN;
    int v = nv[j], c = nc[j];
    float dv = (float)max(n_v_deg[v], 1);
    float dc = (float)max(n_c_deg[c], 1);
    int wb = __float_as_int(rsqrtf(dv * dc));
    int pos  = atomicAdd(&cur_cN[c], 1);
    if (pos >= 0 && pos < ENN) el_cN[pos] = make_int2(v, wb);
    int pos2 = atomicAdd(&cur_vN[v], 1);
    if (pos2 >= 0 && pos2 < ENN) el_vN[pos2] = make_int2(c, wb);
  }
}

// fp32 W[m][k][n] (nmat of 128x128) -> bf16 WT[m][n][k]
__global__ void transpose_sq_kernel(const float* __restrict__ W, bf16* __restrict__ WT, int nmat) {
  int idx = blockIdx.x * 256 + threadIdx.x;
  if (idx < nmat * DIM * DIM) {
    int m = idx / (DIM * DIM); int rc = idx - m * DIM * DIM;
    int r = rc >> 7, c = rc & 127;          // r = k, c = n
    WT[m * DIM * DIM + c * DIM + r] = __float2bfloat16(W[idx]);
  }
}

// fp32 W[k][n] (K x 128) -> bf16 WT[n][k] (128 x K)
__global__ void transpose_kn_kernel(const float* __restrict__ W, bf16* __restrict__ WT, int K) {
  int idx = blockIdx.x * 256 + threadIdx.x;
  if (idx < K * DIM) {
    int r = idx >> 7, c = idx & 127;        // r = k, c = n
    WT[c * K + r] = __float2bfloat16(W[idx]);
  }
}

// ---------------- GEMM helpers (swapped-operand / transposed-output) ----------------
// mfma_f32_32x32x16_bf16 with A = W^T fragment, B = X^T fragment:
//   A: row = lane&31 -> n = nt*32+am, k = (lane>>5)*8 + j   (WT [n][k], 16B contiguous)
//   B: col = lane&31 -> m = r0+am,    k = (lane>>5)*8 + j   (sX row-major, 16B contiguous)
//   D: col = lane&31 = m (one full output row per lane),
//      row = n = (reg&3) + 8*(reg>>2) + 4*(lane>>5)         [m74/m101 verified]

__device__ __forceinline__ void zero_acc(floatx16* acc) {
#pragma unroll
  for (int nt = 0; nt < 4; nt++)
#pragma unroll
    for (int i = 0; i < 16; i++) acc[nt][i] = 0.0f;
}

__device__ __forceinline__ void gemm_k128_T(const short* __restrict__ sIn,
                                            const short* __restrict__ wt, int wstride,
                                            floatx16* acc, int am, int ak, int r0) {
  short8 xfr[8];
#pragma unroll
  for (int kt = 0; kt < 8; kt++)
    xfr[kt] = *(const short8*)&sIn[(r0 + am) * PITCH + kt * 16 + ak];
#pragma unroll
  for (int nt = 0; nt < 4; nt++) {
    const short* wr = wt + (nt * 32 + am) * wstride + ak;
#pragma unroll
    for (int kt = 0; kt < 8; kt++) {
      short8 wfr = *(const short8*)(wr + kt * 16);
      acc[nt] = __builtin_amdgcn_mfma_f32_32x32x16_bf16(wfr, xfr[kt], acc[nt], 0, 0, 0);
    }
  }
}

// Layer1 acc tile (H^T, rows n = layer2's k) + bias + relu -> two layer2 B-fragments
// (kt = 2*nt and 2*nt+1) via pack + permlane32_swap. Lanes L and L+32 hold the SAME
// output column m, so the half-wave swap redistributes k-slots exactly (T12 pattern).
__device__ __forceinline__ void make_bfrags(floatx16 a, const float* __restrict__ B1s,
                                            int nt, int hi4, short8* f0, short8* f1) {
  float v[16];
#pragma unroll
  for (int g = 0; g < 4; g++) {
    float4 bb = *(const float4*)(B1s + nt * 32 + 8 * g + hi4);
    v[4*g+0] = fmaxf(a[4*g+0] + bb.x, 0.0f);
    v[4*g+1] = fmaxf(a[4*g+1] + bb.y, 0.0f);
    v[4*g+2] = fmaxf(a[4*g+2] + bb.z, 0.0f);
    v[4*g+3] = fmaxf(a[4*g+3] + bb.w, 0.0f);
  }
  int w0 = pk2(v[0], v[1]), w1 = pk2(v[2], v[3]), w2 = pk2(v[4], v[5]), w3 = pk2(v[6], v[7]);
  asm("v_permlane32_swap_b32 %0, %1" : "+v"(w0), "+v"(w2));
  asm("v_permlane32_swap_b32 %0, %1" : "+v"(w1), "+v"(w3));
  union { int i[4]; short8 s; } u0;
  u0.i[0] = w0; u0.i[1] = w1; u0.i[2] = w2; u0.i[3] = w3;
  *f0 = u0.s;
  int y0 = pk2(v[8], v[9]), y1 = pk2(v[10], v[11]), y2 = pk2(v[12], v[13]), y3 = pk2(v[14], v[15]);
  asm("v_permlane32_swap_b32 %0, %1" : "+v"(y0), "+v"(y2));
  asm("v_permlane32_swap_b32 %0, %1" : "+v"(y1), "+v"(y3));
  union { int i[4]; short8 s; } u1;
  u1.i[0] = y0; u1.i[1] = y1; u1.i[2] = y2; u1.i[3] = y3;
  *f1 = u1.s;
}

// stage 128 rows x 128 cols: fp32 global -> bf16 padded LDS; optional fp32 passthrough copy.
__device__ __forceinline__ void stage_f32(short* __restrict__ sX, const float* __restrict__ X,
                                          float* __restrict__ cp,
                                          int rb, int nrows, int tid) {
#pragma unroll
  for (int it = 0; it < 16; it++) {
    const int g = it * 1024 + tid * 4;      // float index within 128x128 tile
    const int row = g >> 7, col = g & 127;
    const int grow = rb + row;
    float4 v = make_float4(0.f, 0.f, 0.f, 0.f);
    if (grow < nrows) v = *(const float4*)(X + (size_t)grow * DIM + col);
    union { short s[4]; int2 i2; } pk;
    pk.s[0] = f2bf(v.x); pk.s[1] = f2bf(v.y); pk.s[2] = f2bf(v.z); pk.s[3] = f2bf(v.w);
    *(int2*)&sX[row * PITCH + col] = pk.i2;
    if (cp && grow < nrows) *(float4*)(cp + (size_t)grow * DIM + col) = v;
  }
}

// ---------------- merged dual-MLP messages kernel (V blocks then C blocks) ----------------
__global__ __launch_bounds__(256, 3) void mlp_all_kernel(
    const float* __restrict__ Xv, const float* __restrict__ Xc,
    float* __restrict__ cpv, float* __restrict__ cpc,
    bf16* __restrict__ mo0, bf16* __restrict__ mo1,
    bf16* __restrict__ mo2, bf16* __restrict__ mo3,
    const bf16* __restrict__ w1t, const float* __restrict__ b1,
    const bf16* __restrict__ w2t, const float* __restrict__ b2, int gv) {
  __shared__ short sX[128 * PITCH];
  const int tid = threadIdx.x;
  const float* X; float* cp; bf16 *Y0, *Y1; int i0, nrows, rb;
  if ((int)blockIdx.x < gv) {
    X = Xv; cp = cpv; Y0 = mo0; Y1 = mo1; i0 = 0; nrows = V_SZ; rb = blockIdx.x * 128;
  } else {
    X = Xc; cp = cpc; Y0 = mo2; Y1 = mo3; i0 = 2; nrows = C_SZ; rb = (blockIdx.x - gv) * 128;
  }
  stage_f32(sX, X, cp, rb, nrows, tid);
  __syncthreads();

  const int lane = tid & 63;
  const int w = tid >> 6;
  const int am = lane & 31;
  const int ak = (lane >> 5) * 8;
  const int hi4 = (lane >> 5) * 4;
  const int r0 = w * 32;
  const int m = rb + r0 + am;               // this lane's output row

#pragma unroll 1
  for (int mi = 0; mi < 2; mi++) {
    const int sel = i0 + mi;
    const short* W1s = (const short*)w1t + sel * DIM * DIM;
    const short* W2s = (const short*)w2t + sel * DIM * DIM;
    const float* B1s = b1 + sel * DIM;
    const float* B2s = b2 + sel * DIM;
    bf16* Y = mi ? Y1 : Y0;

    // layer 1 (transposed): acc[nt] = H^T tile, rows n = layer-2 k
    floatx16 acc[4];
    zero_acc(acc);
    gemm_k128_T(sX, W1s, DIM, acc, am, ak, r0);

    // in-register handoff: bias + relu + pack + permlane swap -> layer2 B-frags
    short8 bq[8];
#pragma unroll
    for (int nt = 0; nt < 4; nt++)
      make_bfrags(acc[nt], B1s, nt, hi4, &bq[2 * nt], &bq[2 * nt + 1]);

    // layer 2 (transposed): A = W2^T from global, B = H^T from regs
    floatx16 acc2[4];
    zero_acc(acc2);
#pragma unroll
    for (int nt = 0; nt < 4; nt++) {
      const short* wr = W2s + (nt * 32 + am) * DIM + ak;
#pragma unroll
      for (int kt = 0; kt < 8; kt++) {
        short8 wfr = *(const short8*)(wr + kt * 16);
        acc2[nt] = __builtin_amdgcn_mfma_f32_32x32x16_bf16(wfr, bq[kt], acc2[nt], 0, 0, 0);
      }
    }

    // epilogue: lane owns row m; packed 8B bf16 stores
    if (m < nrows) {
      short* Yp = (short*)Y + (size_t)m * DIM;
#pragma unroll
      for (int nt = 0; nt < 4; nt++) {
#pragma unroll
        for (int g = 0; g < 4; g++) {
          const int n0 = nt * 32 + 8 * g + hi4;
          float4 bb = *(const float4*)(B2s + n0);
          union { short s[4]; int2 v; } pk;
          pk.s[0] = f2bf(acc2[nt][4*g+0] + bb.x);
          pk.s[1] = f2bf(acc2[nt][4*g+1] + bb.y);
          pk.s[2] = f2bf(acc2[nt][4*g+2] + bb.z);
          pk.s[3] = f2bf(acc2[nt][4*g+3] + bb.w);
          *(int2*)&Yp[n0] = pk.v;
        }
      }
    }
  }
}

// ---------------- merged aggregate + concat-GEMM update kernel (C blocks then V blocks) ----------------
__global__ __launch_bounds__(256, 3) void update_all_kernel(
    const float* __restrict__ cemb, const float* __restrict__ vemb,
    const int* __restrict__ rp_cP, const int2* __restrict__ el_cP, const bf16* __restrict__ mq0,
    const int* __restrict__ rp_cN, const int2* __restrict__ el_cN, const bf16* __restrict__ mq1,
    const int* __restrict__ rp_vP, const int2* __restrict__ el_vP, const bf16* __restrict__ mq2,
    const int* __restrict__ rp_vN, const int2* __restrict__ el_vN, const bf16* __restrict__ mq3,
    const bf16* __restrict__ cwt, const float* __restrict__ cbias,
    const bf16* __restrict__ vwt, const float* __restrict__ vbias,
    float* __restrict__ outc, float* __restrict__ outv, int gc) {
  __shared__ short sX[128 * PITCH];
  const int tid = threadIdx.x;
  const float* emb; const int *rpPp, *rpNp; const int2 *elPp, *elNp;
  const bf16 *msgPp, *msgNp, *wt; const float* bias; float* out;
  int nrows, nsrc, rb;
  if ((int)blockIdx.x < gc) {
    emb = cemb; rpPp = rp_cP; elPp = el_cP; msgPp = mq0;
    rpNp = rp_cN; elNp = el_cN; msgNp = mq1;
    wt = cwt; bias = cbias; out = outc; nrows = C_SZ; nsrc = V_SZ; rb = blockIdx.x * 128;
  } else {
    emb = vemb; rpPp = rp_vP; elPp = el_vP; msgPp = mq2;
    rpNp = rp_vN; elNp = el_vN; msgNp = mq3;
    wt = vwt; bias = vbias; out = outv; nrows = V_SZ; nsrc = C_SZ; rb = (blockIdx.x - gc) * 128;
  }
  const int lane = tid & 63, w = tid >> 6;
  const int am = lane & 31, ak = (lane >> 5) * 8, hi4 = (lane >> 5) * 4, r0 = w * 32;

  floatx16 acc[4];
  zero_acc(acc);

#pragma unroll 1
  for (int chunk = 0; chunk < 3; chunk++) {
    if (chunk == 0) {
      stage_f32(sX, emb, nullptr, rb, nrows, tid);
    } else {
      const int* rp = (chunk == 1) ? rpPp : rpNp;
      const int2* el = (chunk == 1) ? elPp : elNp;
      const short* msg = (const short*)((chunk == 1) ? msgPp : msgNp);
      const int ecap = (chunk == 1) ? EPN : ENN;
#pragma unroll 1
      for (int pass = 0; pass < 2; pass++) {
        const int r = pass * 64 + (tid >> 2);
        const int q = tid & 3;
        float a[32];
#pragma unroll
        for (int j = 0; j < 32; j++) a[j] = 0.0f;
        const int grow = rb + r;
        if (grow < nrows) {
          int beg = rp[grow], end = rp[grow + 1];
          beg = max(beg, 0); end = min(end, ecap);   // defensive clamp
          for (int e = beg; e < end; e++) {
            int2 pr = el[e];
            if ((unsigned)pr.x >= (unsigned)nsrc) continue;  // defensive
            float wgt = __int_as_float(pr.y);
            const uint4* mm = (const uint4*)(msg + (size_t)pr.x * DIM + q * 32);
#pragma unroll
            for (int jv = 0; jv < 4; jv++) {
              uint4 u = mm[jv];
              a[jv * 8 + 0] += bflo(u.x) * wgt; a[jv * 8 + 1] += bfhi(u.x) * wgt;
              a[jv * 8 + 2] += bflo(u.y) * wgt; a[jv * 8 + 3] += bfhi(u.y) * wgt;
              a[jv * 8 + 4] += bflo(u.z) * wgt; a[jv * 8 + 5] += bfhi(u.z) * wgt;
              a[jv * 8 + 6] += bflo(u.w) * wgt; a[jv * 8 + 7] += bfhi(u.w) * wgt;
            }
          }
        }
        int4* dst = (int4*)&sX[r * PITCH + q * 32];
#pragma unroll
        for (int jv = 0; jv < 4; jv++) {
          union { short s[8]; int4 v; } pk;
#pragma unroll
          for (int i = 0; i < 8; i++) pk.s[i] = f2bf(a[jv * 8 + i]);
          dst[jv] = pk.v;
        }
      }
    }
    __syncthreads();
    gemm_k128_T(sX, (const short*)wt + chunk * DIM, 3 * DIM, acc, am, ak, r0);
    __syncthreads();
  }

  // epilogue: lane owns row m; packed float4 stores
  const int m = rb + r0 + am;
  if (m < nrows) {
    float* op = out + (size_t)m * DIM;
#pragma unroll
    for (int nt = 0; nt < 4; nt++) {
#pragma unroll
      for (int g = 0; g < 4; g++) {
        const int n0 = nt * 32 + 8 * g + hi4;
        float4 bb = *(const float4*)(bias + n0);
        float4 r;
        r.x = acc[nt][4*g+0] + bb.x;
        r.y = acc[nt][4*g+1] + bb.y;
        r.z = acc[nt][4*g+2] + bb.z;
        r.w = acc[nt][4*g+3] + bb.w;
        *(float4*)&op[n0] = r;
      }
    }
  }
}

// ---------------- host ----------------

static void run_scan(int* deg, int* rp, int* bsum, int n, hipStream_t s) {
  int nb = (n + 1023) / 1024;
  scan_phase1<<<nb, 256, 0, s>>>(deg, rp, bsum, n);
  scan_phase2<<<1, 256, 0, s>>>(bsum, nb, rp + n);
  scan_phase3<<<(n + 255) / 256, 256, 0, s>>>(rp, bsum, n);
}

extern "C" void kernel_launch(void* const* d_in, const int* in_sizes, int n_in,
                              void* d_out, int out_size, void* d_ws, size_t ws_size,
                              hipStream_t stream) {
  const int* v_ei = (const int*)d_in[2];
  const int* c_ei = (const int*)d_in[3];
  const int* p_ei = (const int*)d_in[4];
  const int* n_ei = (const int*)d_in[5];
  const float* v_emb = (const float*)d_in[6];
  const float* c_emb = (const float*)d_in[7];
  const float* W1 = (const float*)d_in[8];
  const float* B1 = (const float*)d_in[9];
  const float* W2 = (const float*)d_in[10];
  const float* B2 = (const float*)d_in[11];
  const float* cW = (const float*)d_in[12];
  const float* cB = (const float*)d_in[13];
  const float* vW = (const float*)d_in[14];
  const float* vB = (const float*)d_in[15];
  float* out = (float*)d_out;

  char* p = (char*)d_ws;
  auto alloc = [&](size_t bytes) -> char* {
    char* r = p; p += (bytes + 255) & ~(size_t)255; return r;
  };

  int* pv = (int*)alloc((size_t)EPN * 4);
  int* pc = (int*)alloc((size_t)EPN * 4);
  int* nv = (int*)alloc((size_t)ENN * 4);
  int* nc = (int*)alloc((size_t)ENN * 4);
  int* degs = (int*)alloc((size_t)(2 * V_SZ + 2 * C_SZ) * 4);
  int* p_v_deg = degs;
  int* n_v_deg = degs + V_SZ;
  int* p_c_deg = degs + 2 * V_SZ;
  int* n_c_deg = degs + 2 * V_SZ + C_SZ;
  int* rp_cP = (int*)alloc((size_t)(C_SZ + 1) * 4);
  int* rp_cN = (int*)alloc((size_t)(C_SZ + 1) * 4);
  int* rp_vP = (int*)alloc((size_t)(V_SZ + 1) * 4);
  int* rp_vN = (int*)alloc((size_t)(V_SZ + 1) * 4);
  int* cur_cP = (int*)alloc((size_t)C_SZ * 4);
  int* cur_cN = (int*)alloc((size_t)C_SZ * 4);
  int* cur_vP = (int*)alloc((size_t)V_SZ * 4);
  int* cur_vN = (int*)alloc((size_t)V_SZ * 4);
  int* bsum = (int*)alloc(256 * 4);
  int2* el_cP = (int2*)alloc((size_t)EPN * 8);
  int2* el_cN = (int2*)alloc((size_t)ENN * 8);
  int2* el_vP = (int2*)alloc((size_t)EPN * 8);
  int2* el_vN = (int2*)alloc((size_t)ENN * 8);
  bf16* w1t = (bf16*)alloc((size_t)4 * DIM * DIM * 2);
  bf16* w2t = (bf16*)alloc((size_t)4 * DIM * DIM * 2);
  bf16* cwt = (bf16*)alloc((size_t)DIM * 3 * DIM * 2);
  bf16* vwt = (bf16*)alloc((size_t)DIM * 3 * DIM * 2);
  bf16* m0 = (bf16*)alloc((size_t)V_SZ * DIM * 2);
  bf16* m1 = (bf16*)alloc((size_t)V_SZ * DIM * 2);
  bf16* m2 = (bf16*)alloc((size_t)C_SZ * DIM * 2);
  bf16* m3 = (bf16*)alloc((size_t)C_SZ * DIM * 2);

  // ---- per-call graph prep (ws is re-poisoned before every launch) ----
  hipMemsetAsync(degs, 0, (size_t)(2 * V_SZ + 2 * C_SZ) * 4, stream);
  hist_kernel<<<(EPN + ENN + 255) / 256, 256, 0, stream>>>(
      v_ei, c_ei, p_ei, n_ei, pv, pc, nv, nc, p_v_deg, p_c_deg, n_v_deg, n_c_deg);
  run_scan(p_c_deg, rp_cP, bsum, C_SZ, stream);
  run_scan(n_c_deg, rp_cN, bsum, C_SZ, stream);
  run_scan(p_v_deg, rp_vP, bsum, V_SZ, stream);
  run_scan(n_v_deg, rp_vN, bsum, V_SZ, stream);
  hipMemcpyAsync(cur_cP, rp_cP, (size_t)C_SZ * 4, hipMemcpyDeviceToDevice, stream);
  hipMemcpyAsync(cur_cN, rp_cN, (size_t)C_SZ * 4, hipMemcpyDeviceToDevice, stream);
  hipMemcpyAsync(cur_vP, rp_vP, (size_t)V_SZ * 4, hipMemcpyDeviceToDevice, stream);
  hipMemcpyAsync(cur_vN, rp_vN, (size_t)V_SZ * 4, hipMemcpyDeviceToDevice, stream);
  fill_kernel<<<(EPN + ENN + 255) / 256, 256, 0, stream>>>(
      pv, pc, nv, nc, p_v_deg, p_c_deg, n_v_deg, n_c_deg,
      cur_cP, cur_cN, cur_vP, cur_vN, el_cP, el_cN, el_vP, el_vN);
  transpose_sq_kernel<<<(4 * DIM * DIM + 255) / 256, 256, 0, stream>>>(W1, w1t, 4);
  transpose_sq_kernel<<<(4 * DIM * DIM + 255) / 256, 256, 0, stream>>>(W2, w2t, 4);
  transpose_kn_kernel<<<(3 * DIM * DIM + 255) / 256, 256, 0, stream>>>(cW, cwt, 3 * DIM);
  transpose_kn_kernel<<<(3 * DIM * DIM + 255) / 256, 256, 0, stream>>>(vW, vwt, 3 * DIM);

  float* vout[NITER + 1];
  float* cout[NITER + 1];
  for (int t = 0; t <= NITER; t++) {
    vout[t] = out + (size_t)t * V_SZ * DIM;
    cout[t] = out + (size_t)5 * V_SZ * DIM + (size_t)t * C_SZ * DIM;
  }

  const int gv = (V_SZ + 127) / 128;
  const int gc = (C_SZ + 127) / 128;
  for (int t = 0; t < NITER; t++) {
    const float* xv = t ? (const float*)vout[t] : v_emb;
    const float* xc = t ? (const float*)cout[t] : c_emb;
    // merged message MLPs (V + C); t==0 additionally writes the fp32 passthrough copies
    mlp_all_kernel<<<gv + gc, 256, 0, stream>>>(
        xv, xc, t ? nullptr : vout[0], t ? nullptr : cout[0],
        m0, m1, m2, m3, w1t, B1, w2t, B2, gv);
    // merged updates (C + V)
    update_all_kernel<<<gc + gv, 256, 0, stream>>>(
        xc, xv,
        rp_cP, el_cP, m0, rp_cN, el_cN, m1,
        rp_vP, el_vP, m2, rp_vN, el_vN, m3,
        cwt, cB, vwt, vB, cout[t + 1], vout[t + 1], gc);
  }
}